// Round 6
// baseline (228.584 us; speedup 1.0000x reference)
//
#include <hip/hip_runtime.h>
#include <hip/hip_bf16.h>

typedef __bf16 bf16;
typedef __bf16 bf16x8 __attribute__((ext_vector_type(8)));
typedef float f32x4 __attribute__((ext_vector_type(4)));

static __device__ __forceinline__ f32x4 mfma16(bf16x8 a, bf16x8 b, f32x4 c) {
  return __builtin_amdgcn_mfma_f32_16x16x32_bf16(a, b, c, 0, 0, 0);
}

// No-drain workgroup barrier: waits only LDS ops (lgkmcnt), leaves global
// loads (vmcnt) in flight across the barrier. (r5: null vs __syncthreads,
// kept because harmless and correct.)
static __device__ __forceinline__ void wg_barrier() {
  asm volatile("s_waitcnt lgkmcnt(0)" ::: "memory");
  __builtin_amdgcn_s_barrier();
  asm volatile("" ::: "memory");
}

static __device__ __forceinline__ bf16x8 cvt8(const float* p) {
  f32x4 a0 = *(const f32x4*)p;
  f32x4 a1 = *(const f32x4*)(p + 4);
  bf16x8 r;
#pragma unroll
  for (int j = 0; j < 4; ++j) { r[j] = (bf16)a0[j]; r[4 + j] = (bf16)a1[j]; }
  return r;
}

// ---------------------------------------------------------------------------
// prep_wt: write W in MFMA B-fragment order so qkv_gemm's B loads are fully
// coalesced (1024B per wave instruction instead of 16 scattered rows).
// ---------------------------------------------------------------------------
__global__ void prep_wt(const float* __restrict__ Wq, const float* __restrict__ Wk,
                        const float* __restrict__ Wv, bf16* __restrict__ Wf) {
  int k = blockIdx.x;   // 0..255
  int c = threadIdx.x;  // 0..319
  float v;
  if (c < 32)       v = Wq[k * 32 + c];
  else if (c < 64)  v = Wk[k * 32 + (c - 32)];
  else              v = Wv[k * 256 + (c - 64)];
  int t5 = c >> 6, ct = (c >> 4) & 3, lwc = c & 15;
  int kc = k >> 5, qq = (k >> 3) & 3, ke = k & 7;
  Wf[((((t5 * 8 + kc) * 4 + ct) * 64) + qq * 16 + lwc) * 8 + ke] = (bf16)v;
}

// ---------------------------------------------------------------------------
// qkv_gemm: one block per 64-row tile; x A-frags loaded ONCE into registers,
// then looped over all 5 column tiles (Q|K|V). V epilogue via LDS transpose.
// B-frags come from the frag-major Wf layout (coalesced).
// ---------------------------------------------------------------------------
__global__ __launch_bounds__(256) void qkv_gemm(
    const float* __restrict__ x, const bf16* __restrict__ Wf,
    const float* __restrict__ bq, const float* __restrict__ bk,
    const float* __restrict__ bv,
    bf16* __restrict__ Qd, bf16* __restrict__ Kd, bf16* __restrict__ Vt) {
  __shared__ __align__(16) bf16 tile[64 * 72];
  int tid = threadIdx.x;
  int lane = tid & 63, w = tid >> 6;
  int lw = lane & 15, qq = lane >> 4;
  int r0 = blockIdx.x * 64;
  int bb = r0 >> 12, n0 = r0 & 4095;

  const float* arow = x + (size_t)(r0 + 16 * w + lw) * 256;
  bf16x8 a[8];
#pragma unroll
  for (int kc = 0; kc < 8; ++kc) a[kc] = cvt8(arow + kc * 32 + qq * 8);

  for (int c0 = 0; c0 < 320; c0 += 64) {
    int t5 = c0 >> 6;
    f32x4 acc[4] = {};
#pragma unroll
    for (int kc = 0; kc < 8; ++kc)
#pragma unroll
      for (int t = 0; t < 4; ++t) {
        bf16x8 b = *(const bf16x8*)(Wf + ((size_t)(((t5 * 8 + kc) * 4 + t) * 64) + lane) * 8);
        acc[t] = mfma16(a[kc], b, acc[t]);
      }
    // C/D: col = lane&15, row = (lane>>4)*4 + i
    if (c0 == 0) {
#pragma unroll
      for (int t = 0; t < 4; ++t) {
        int c = 16 * t + lw;
        float bias = (c < 32) ? bq[c] : bk[c - 32];
#pragma unroll
        for (int i = 0; i < 4; ++i) {
          int n = n0 + 16 * w + 4 * qq + i;
          bf16 hv = (bf16)(acc[t][i] + bias);
          if (c < 32) Qd[((size_t)(bb << 12) + n) * 32 + c] = hv;
          else        Kd[((size_t)(bb << 12) + n) * 32 + (c - 32)] = hv;
        }
      }
    } else {
#pragma unroll
      for (int t = 0; t < 4; ++t) {
        int cl = 16 * t + lw;
        float bias = bv[c0 - 64 + cl];
#pragma unroll
        for (int i = 0; i < 4; ++i)
          tile[cl * 72 + 16 * w + 4 * qq + i] = (bf16)(acc[t][i] + bias);
      }
      __syncthreads();
      int nl = tid & 63;
#pragma unroll
      for (int it = 0; it < 16; ++it) {
        int cl = 4 * it + w;  // wave-uniform col -> 128B contiguous stores
        Vt[((size_t)bb * 256 + (c0 - 64) + cl) * 4096 + n0 + nl] = tile[cl * 72 + nl];
      }
      __syncthreads();
    }
  }
}

// ---------------------------------------------------------------------------
// flash_attn: 32-row q-tiles, 512 threads (8 waves), grid (128, B).
// 512 blocks -> 2 resident 8-wave blocks per CU = 16 waves/CU = 4 waves/SIMD
// (r0/r5 had 2/SIMD; r4's "split" kept 2/SIMD and proved nothing about TLP).
// Two independent barrier domains + doubled TLP hide the serial per-tile
// chain (af-read -> PV; QK -> exp -> P-write -> barrier).
// Per-CU accounting vs r0: QK/exp/P-write/PV totals identical; P LDS reads
// identical; V traffic x2 (~80KB/tile/CU, well under L1/L2 ceilings).
// Wave w: S-subtile rows 16*(w&1), cols 16*(w>>1); PV channels [32w, 32w+32).
// No s_setprio. Deferred l-sum, double-buffered P, one wg_barrier per tile.
// Body macro-specialized with LITERAL buffer names (runtime-indexed register
// arrays demote to scratch).
// ---------------------------------------------------------------------------
__global__ __launch_bounds__(512, 4) void flash_attn(
    const bf16* __restrict__ Qd, const bf16* __restrict__ Kd,
    const bf16* __restrict__ Vt, const float* __restrict__ x,
    const float* __restrict__ gamma, float* __restrict__ out) {
  __shared__ __align__(16) bf16 Pl[2][32 * 72];
  __shared__ __align__(16) float lsum4[4][32];

  int tid = threadIdx.x;
  int lane = tid & 63, w = tid >> 6;   // w in 0..7
  int lw = lane & 15, qq = lane >> 4;
  int wr = w & 1, wq = w >> 1;         // S rows 16*wr, S cols 16*wq
  int colb = 16 * wq, chb = 32 * w;
  int bb = blockIdx.y;
  int r0 = blockIdx.x * 32;

  const bf16* Qb = Qd + ((size_t)bb << 12) * 32;
  const bf16* Kb = Kd + ((size_t)bb << 12) * 32;
  const bf16* Vb = Vt + (size_t)bb * 256 * 4096;

  bf16x8 qf = *(const bf16x8*)(Qb + (size_t)(r0 + 16 * wr + lw) * 32 + qq * 8);

  f32x4 o[2][2] = {};
  float l_part[4] = {};
  bf16x8 kbuf0, kbuf1, vbuf0[4], vbuf1[4];

  // ---- prologue: S(0) -> Pl[0]; prefetch K(1), V(0) ----
  kbuf0 = *(const bf16x8*)(Kb + (size_t)(colb + lw) * 32 + qq * 8);
  {
    f32x4 z = {};
    f32x4 s = mfma16(qf, kbuf0, z);
#pragma unroll
    for (int i = 0; i < 4; ++i) {
      float p = __expf(s[i]);
      l_part[i] += p;
      Pl[0][(16 * wr + 4 * qq + i) * 72 + colb + lw] = (bf16)p;
    }
  }
  kbuf1 = *(const bf16x8*)(Kb + (size_t)(64 + colb + lw) * 32 + qq * 8);
#pragma unroll
  for (int t = 0; t < 2; ++t)
#pragma unroll
    for (int kc = 0; kc < 2; ++kc)
      vbuf0[t * 2 + kc] = *(const bf16x8*)(Vb + (size_t)(chb + 16 * t + lw) * 4096 + kc * 32 + qq * 8);
  wg_barrier();

  // BODY(j, PCUR, PNXT, KN, KC, VC, VN): literal register-buffer names.
#define FA_BODY(J, PCUR, PNXT, KN, KC, VC, VN)                                     \
  {                                                                                \
    const int j = (J);                                                             \
    int n1 = ((j + 1) & 63) * 64, n2 = ((j + 2) & 63) * 64;                        \
    bf16x8 af[2][2];                                                               \
    _Pragma("unroll") for (int m = 0; m < 2; ++m)                                  \
      _Pragma("unroll") for (int kc = 0; kc < 2; ++kc)                             \
        af[m][kc] = *(const bf16x8*)&Pl[PCUR][(16 * m + lw) * 72 + kc * 32 + qq * 8]; \
    if (j < 63) {                                                                  \
      f32x4 z = {};                                                                \
      f32x4 s = mfma16(qf, KN, z);                                                 \
      _Pragma("unroll") for (int i = 0; i < 4; ++i) {                              \
        float p = __expf(s[i]);                                                    \
        l_part[i] += p;                                                            \
        Pl[PNXT][(16 * wr + 4 * qq + i) * 72 + colb + lw] = (bf16)p;               \
      }                                                                            \
      KC = *(const bf16x8*)(Kb + (size_t)(n2 + colb + lw) * 32 + qq * 8);          \
    }                                                                              \
    _Pragma("unroll") for (int t = 0; t < 2; ++t)                                  \
      _Pragma("unroll") for (int kc = 0; kc < 2; ++kc)                             \
        VN[t * 2 + kc] = *(const bf16x8*)(Vb + (size_t)(chb + 16 * t + lw) * 4096 + n1 + kc * 32 + qq * 8); \
    _Pragma("unroll") for (int kc = 0; kc < 2; ++kc)                               \
      _Pragma("unroll") for (int t = 0; t < 2; ++t)                                \
        _Pragma("unroll") for (int m = 0; m < 2; ++m)                              \
          o[m][t] = mfma16(af[m][kc], VC[t * 2 + kc], o[m][t]);                    \
    wg_barrier();                                                                  \
  }

  for (int jj = 0; jj < 32; ++jj) {
    FA_BODY(2 * jj,     0, 1, kbuf1, kbuf0, vbuf0, vbuf1)
    FA_BODY(2 * jj + 1, 1, 0, kbuf0, kbuf1, vbuf1, vbuf0)
  }
#undef FA_BODY

  // ---- l reduction: sum over this wave's 16 cols, then across 4 col-waves ----
#pragma unroll
  for (int i = 0; i < 4; ++i) {
    float v = l_part[i];
    v += __shfl_xor(v, 1);
    v += __shfl_xor(v, 2);
    v += __shfl_xor(v, 4);
    v += __shfl_xor(v, 8);
    if (lw == 0) lsum4[wq][16 * wr + 4 * qq + i] = v;
  }
  __syncthreads();

  float g = gamma[0];
#pragma unroll
  for (int m = 0; m < 2; ++m) {
    f32x4 l0 = *(const f32x4*)&lsum4[0][16 * m + 4 * qq];
    f32x4 l1 = *(const f32x4*)&lsum4[1][16 * m + 4 * qq];
    f32x4 l2 = *(const f32x4*)&lsum4[2][16 * m + 4 * qq];
    f32x4 l3 = *(const f32x4*)&lsum4[3][16 * m + 4 * qq];
#pragma unroll
    for (int i = 0; i < 4; ++i) {
      float rinv = 1.f / (l0[i] + l1[i] + l2[i] + l3[i]);
      int row = r0 + 16 * m + 4 * qq + i;
      size_t base = (((size_t)bb << 12) + row) * 256 + chb;
#pragma unroll
      for (int t = 0; t < 2; ++t)
        out[base + 16 * t + lw] = g * (o[m][t][i] * rinv) + x[base + 16 * t + lw];
    }
  }
}

extern "C" void kernel_launch(void* const* d_in, const int* in_sizes, int n_in,
                              void* d_out, int out_size, void* d_ws, size_t ws_size,
                              hipStream_t stream) {
  const float* x     = (const float*)d_in[0];
  const float* Wq    = (const float*)d_in[1];
  const float* bq    = (const float*)d_in[2];
  const float* Wk    = (const float*)d_in[3];
  const float* bk    = (const float*)d_in[4];
  const float* Wv    = (const float*)d_in[5];
  const float* bv    = (const float*)d_in[6];
  const float* gamma = (const float*)d_in[7];
  float* out = (float*)d_out;

  const size_t WT_E = 320 * 256;
  const size_t QK_E = (size_t)4096 * 32;
  const size_t VT_E = (size_t)256 * 4096;
  size_t full_bytes = (WT_E + 4 * 2 * QK_E + 4 * VT_E) * sizeof(bf16);

  bf16* Wf = (bf16*)d_ws;
  prep_wt<<<dim3(256), dim3(320), 0, stream>>>(Wq, Wk, Wv, Wf);

  if (ws_size >= full_bytes) {
    bf16* Qd = Wf + WT_E;
    bf16* Kd = Qd + 4 * QK_E;
    bf16* Vt = Kd + 4 * QK_E;
    qkv_gemm<<<dim3(256), dim3(256), 0, stream>>>(x, Wf, bq, bk, bv, Qd, Kd, Vt);
    flash_attn<<<dim3(128, 4), dim3(512), 0, stream>>>(Qd, Kd, Vt, x, gamma, out);
  } else {
    bf16* Qd = Wf + WT_E;
    bf16* Kd = Qd + QK_E;
    bf16* Vt = Kd + QK_E;
    for (int b = 0; b < 4; ++b) {
      const float* xb = x + (size_t)b * 4096 * 256;
      float* outb = out + (size_t)b * 4096 * 256;
      qkv_gemm<<<dim3(64), dim3(256), 0, stream>>>(xb, Wf, bq, bk, bv, Qd, Kd, Vt);
      flash_attn<<<dim3(128, 1), dim3(512), 0, stream>>>(Qd, Kd, Vt, xb, gamma, outb);
    }
  }
}

// Round 7
// 168.883 us; speedup vs baseline: 1.3535x; 1.3535x over previous
//
#include <hip/hip_runtime.h>
#include <hip/hip_bf16.h>

typedef __bf16 bf16;
typedef __bf16 bf16x8 __attribute__((ext_vector_type(8)));
typedef float f32x4 __attribute__((ext_vector_type(4)));

static __device__ __forceinline__ f32x4 mfma16(bf16x8 a, bf16x8 b, f32x4 c) {
  return __builtin_amdgcn_mfma_f32_16x16x32_bf16(a, b, c, 0, 0, 0);
}

// No-drain workgroup barrier: waits only LDS ops (lgkmcnt), leaves global
// loads (vmcnt) in flight across the barrier (r5: neutral vs __syncthreads,
// kept — required here so the distance-2 V prefetch actually spans tiles).
static __device__ __forceinline__ void wg_barrier() {
  asm volatile("s_waitcnt lgkmcnt(0)" ::: "memory");
  __builtin_amdgcn_s_barrier();
  asm volatile("" ::: "memory");
}

static __device__ __forceinline__ bf16x8 cvt8(const float* p) {
  f32x4 a0 = *(const f32x4*)p;
  f32x4 a1 = *(const f32x4*)(p + 4);
  bf16x8 r;
#pragma unroll
  for (int j = 0; j < 4; ++j) { r[j] = (bf16)a0[j]; r[4 + j] = (bf16)a1[j]; }
  return r;
}

// ---------------------------------------------------------------------------
// prep_wt: write W in MFMA B-fragment order so qkv_gemm's B loads are fully
// coalesced (1024B per wave instruction instead of 16 scattered rows).
// ---------------------------------------------------------------------------
__global__ void prep_wt(const float* __restrict__ Wq, const float* __restrict__ Wk,
                        const float* __restrict__ Wv, bf16* __restrict__ Wf) {
  int k = blockIdx.x;   // 0..255
  int c = threadIdx.x;  // 0..319
  float v;
  if (c < 32)       v = Wq[k * 32 + c];
  else if (c < 64)  v = Wk[k * 32 + (c - 32)];
  else              v = Wv[k * 256 + (c - 64)];
  int t5 = c >> 6, ct = (c >> 4) & 3, lwc = c & 15;
  int kc = k >> 5, qq = (k >> 3) & 3, ke = k & 7;
  Wf[((((t5 * 8 + kc) * 4 + ct) * 64) + qq * 16 + lwc) * 8 + ke] = (bf16)v;
}

// ---------------------------------------------------------------------------
// qkv_gemm: one block per 64-row tile; x A-frags loaded ONCE into registers,
// then looped over all 5 column tiles (Q|K|V). V epilogue via LDS transpose.
// B-frags come from the frag-major Wf layout (coalesced).
// ---------------------------------------------------------------------------
__global__ __launch_bounds__(256) void qkv_gemm(
    const float* __restrict__ x, const bf16* __restrict__ Wf,
    const float* __restrict__ bq, const float* __restrict__ bk,
    const float* __restrict__ bv,
    bf16* __restrict__ Qd, bf16* __restrict__ Kd, bf16* __restrict__ Vt) {
  __shared__ __align__(16) bf16 tile[64 * 72];
  int tid = threadIdx.x;
  int lane = tid & 63, w = tid >> 6;
  int lw = lane & 15, qq = lane >> 4;
  int r0 = blockIdx.x * 64;
  int bb = r0 >> 12, n0 = r0 & 4095;

  const float* arow = x + (size_t)(r0 + 16 * w + lw) * 256;
  bf16x8 a[8];
#pragma unroll
  for (int kc = 0; kc < 8; ++kc) a[kc] = cvt8(arow + kc * 32 + qq * 8);

  for (int c0 = 0; c0 < 320; c0 += 64) {
    int t5 = c0 >> 6;
    f32x4 acc[4] = {};
#pragma unroll
    for (int kc = 0; kc < 8; ++kc)
#pragma unroll
      for (int t = 0; t < 4; ++t) {
        bf16x8 b = *(const bf16x8*)(Wf + ((size_t)(((t5 * 8 + kc) * 4 + t) * 64) + lane) * 8);
        acc[t] = mfma16(a[kc], b, acc[t]);
      }
    // C/D: col = lane&15, row = (lane>>4)*4 + i
    if (c0 == 0) {
#pragma unroll
      for (int t = 0; t < 4; ++t) {
        int c = 16 * t + lw;
        float bias = (c < 32) ? bq[c] : bk[c - 32];
#pragma unroll
        for (int i = 0; i < 4; ++i) {
          int n = n0 + 16 * w + 4 * qq + i;
          bf16 hv = (bf16)(acc[t][i] + bias);
          if (c < 32) Qd[((size_t)(bb << 12) + n) * 32 + c] = hv;
          else        Kd[((size_t)(bb << 12) + n) * 32 + (c - 32)] = hv;
        }
      }
    } else {
#pragma unroll
      for (int t = 0; t < 4; ++t) {
        int cl = 16 * t + lw;
        float bias = bv[c0 - 64 + cl];
#pragma unroll
        for (int i = 0; i < 4; ++i)
          tile[cl * 72 + 16 * w + 4 * qq + i] = (bf16)(acc[t][i] + bias);
      }
      __syncthreads();
      int nl = tid & 63;
#pragma unroll
      for (int it = 0; it < 16; ++it) {
        int cl = 4 * it + w;  // wave-uniform col -> 128B contiguous stores
        Vt[((size_t)bb * 256 + (c0 - 64) + cl) * 4096 + n0 + nl] = tile[cl * 72 + nl];
      }
      __syncthreads();
    }
  }
}

// ---------------------------------------------------------------------------
// flash_attn: r0 geometry (64-row q-tiles, 512 threads/8 waves, grid(64,4),
// 1 block/CU, no setprio) with ONE change: V prefetch distance 2 via FOUR
// register V-buffers (rotation period 4). Body j consumes V(j) that was
// issued back at body j-2 (~3000 cyc earlier), so the V miss latency
// (L2 ~300 / HBM ~900 cyc) is fully covered instead of stalling every
// wave at the start of PV (r6 diagnosis: all waves phase-locked on the
// same V stall; TLP could not hide it).
// Wave w: S-subtile rows 16*(w&3), cols 32*(w>>2); PV channels [32w,+32).
// Deferred l-sum, double-buffered P, one wg_barrier per tile. Body macro-
// specialized with LITERAL buffer names (runtime-indexed register arrays
// demote to scratch). Unroll 4 = LCM(P period 2, V period 4).
// ---------------------------------------------------------------------------
__global__ __launch_bounds__(512, 2) void flash_attn(
    const bf16* __restrict__ Qd, const bf16* __restrict__ Kd,
    const bf16* __restrict__ Vt, const float* __restrict__ x,
    const float* __restrict__ gamma, float* __restrict__ out) {
  __shared__ __align__(16) bf16 Pl[2][64 * 72];
  __shared__ __align__(16) float lsum2[2][64];

  int tid = threadIdx.x;
  int lane = tid & 63, w = tid >> 6;
  int lw = lane & 15, qq = lane >> 4;
  int wr = w & 3, wc = w >> 2, chb = 32 * w;
  int bb = blockIdx.y;
  int r0 = blockIdx.x * 64;

  const bf16* Qb = Qd + ((size_t)bb << 12) * 32;
  const bf16* Kb = Kd + ((size_t)bb << 12) * 32;
  const bf16* Vb = Vt + (size_t)bb * 256 * 4096;

  bf16x8 qf = *(const bf16x8*)(Qb + (size_t)(r0 + 16 * wr + lw) * 32 + qq * 8);

  f32x4 o[4][2] = {};
  float l_part[4] = {};
  bf16x8 kbuf0[2], kbuf1[2];
  bf16x8 vbufA[4], vbufB[4], vbufC[4], vbufD[4];

  // ---- prologue: S(0) -> Pl[0]; prefetch K(1), V(0), V(1) ----
#pragma unroll
  for (int t = 0; t < 2; ++t)
    kbuf0[t] = *(const bf16x8*)(Kb + (size_t)(32 * wc + 16 * t + lw) * 32 + qq * 8);
  {
    f32x4 s[2];
#pragma unroll
    for (int t = 0; t < 2; ++t) { f32x4 z = {}; s[t] = mfma16(qf, kbuf0[t], z); }
#pragma unroll
    for (int t = 0; t < 2; ++t)
#pragma unroll
      for (int i = 0; i < 4; ++i) {
        float p = __expf(s[t][i]);
        l_part[i] += p;
        Pl[0][(16 * wr + 4 * qq + i) * 72 + 32 * wc + 16 * t + lw] = (bf16)p;
      }
  }
#pragma unroll
  for (int t = 0; t < 2; ++t)
    kbuf1[t] = *(const bf16x8*)(Kb + (size_t)(64 + 32 * wc + 16 * t + lw) * 32 + qq * 8);
#pragma unroll
  for (int t = 0; t < 2; ++t)
#pragma unroll
    for (int kc = 0; kc < 2; ++kc) {
      vbufA[t * 2 + kc] = *(const bf16x8*)(Vb + (size_t)(chb + 16 * t + lw) * 4096 + kc * 32 + qq * 8);
      vbufB[t * 2 + kc] = *(const bf16x8*)(Vb + (size_t)(chb + 16 * t + lw) * 4096 + 64 + kc * 32 + qq * 8);
    }
  wg_barrier();

  // BODY(j, PCUR, PNXT, KN, KC, VC, VN): literal register-buffer names.
  // Consumes P(j) from Pl[PCUR] and V(j) from VC; computes S(j+1) with KN;
  // prefetches K(j+2) into KC and V(j+2) into VN (distance 2).
#define FA_BODY(J, PCUR, PNXT, KN, KC, VC, VN)                                     \
  {                                                                                \
    const int j = (J);                                                             \
    int n2 = ((j + 2) & 63) * 64;                                                  \
    bf16x8 af[4][2];                                                               \
    _Pragma("unroll") for (int m = 0; m < 4; ++m)                                  \
      _Pragma("unroll") for (int kc = 0; kc < 2; ++kc)                             \
        af[m][kc] = *(const bf16x8*)&Pl[PCUR][(16 * m + lw) * 72 + kc * 32 + qq * 8]; \
    if (j < 63) {                                                                  \
      f32x4 s[2];                                                                  \
      _Pragma("unroll") for (int t = 0; t < 2; ++t) {                              \
        f32x4 z = {};                                                              \
        s[t] = mfma16(qf, KN[t], z);                                               \
      }                                                                            \
      _Pragma("unroll") for (int t = 0; t < 2; ++t)                                \
        _Pragma("unroll") for (int i = 0; i < 4; ++i) {                            \
          float p = __expf(s[t][i]);                                               \
          l_part[i] += p;                                                          \
          Pl[PNXT][(16 * wr + 4 * qq + i) * 72 + 32 * wc + 16 * t + lw] = (bf16)p; \
        }                                                                          \
      _Pragma("unroll") for (int t = 0; t < 2; ++t)                                \
        KC[t] = *(const bf16x8*)(Kb + (size_t)(n2 + 32 * wc + 16 * t + lw) * 32 + qq * 8); \
    }                                                                              \
    _Pragma("unroll") for (int t = 0; t < 2; ++t)                                  \
      _Pragma("unroll") for (int kc = 0; kc < 2; ++kc)                             \
        VN[t * 2 + kc] = *(const bf16x8*)(Vb + (size_t)(chb + 16 * t + lw) * 4096 + n2 + kc * 32 + qq * 8); \
    _Pragma("unroll") for (int kc = 0; kc < 2; ++kc)                               \
      _Pragma("unroll") for (int t = 0; t < 2; ++t)                                \
        _Pragma("unroll") for (int m = 0; m < 4; ++m)                              \
          o[m][t] = mfma16(af[m][kc], VC[t * 2 + kc], o[m][t]);                    \
    wg_barrier();                                                                  \
  }

  for (int jj = 0; jj < 16; ++jj) {
    FA_BODY(4 * jj,     0, 1, kbuf1, kbuf0, vbufA, vbufC)
    FA_BODY(4 * jj + 1, 1, 0, kbuf0, kbuf1, vbufB, vbufD)
    FA_BODY(4 * jj + 2, 0, 1, kbuf1, kbuf0, vbufC, vbufA)
    FA_BODY(4 * jj + 3, 1, 0, kbuf0, kbuf1, vbufD, vbufB)
  }
#undef FA_BODY

  // ---- l reduction ----
#pragma unroll
  for (int i = 0; i < 4; ++i) {
    float v = l_part[i];
    v += __shfl_xor(v, 1);
    v += __shfl_xor(v, 2);
    v += __shfl_xor(v, 4);
    v += __shfl_xor(v, 8);
    if (lw == 0) lsum2[wc][16 * wr + 4 * qq + i] = v;
  }
  __syncthreads();

  float g = gamma[0];
#pragma unroll
  for (int m = 0; m < 4; ++m) {
    f32x4 la = *(const f32x4*)&lsum2[0][16 * m + 4 * qq];
    f32x4 lb = *(const f32x4*)&lsum2[1][16 * m + 4 * qq];
#pragma unroll
    for (int i = 0; i < 4; ++i) {
      float rinv = 1.f / (la[i] + lb[i]);
      int row = r0 + 16 * m + 4 * qq + i;
      size_t base = (((size_t)bb << 12) + row) * 256 + chb;
#pragma unroll
      for (int t = 0; t < 2; ++t)
        out[base + 16 * t + lw] = g * (o[m][t][i] * rinv) + x[base + 16 * t + lw];
    }
  }
}

extern "C" void kernel_launch(void* const* d_in, const int* in_sizes, int n_in,
                              void* d_out, int out_size, void* d_ws, size_t ws_size,
                              hipStream_t stream) {
  const float* x     = (const float*)d_in[0];
  const float* Wq    = (const float*)d_in[1];
  const float* bq    = (const float*)d_in[2];
  const float* Wk    = (const float*)d_in[3];
  const float* bk    = (const float*)d_in[4];
  const float* Wv    = (const float*)d_in[5];
  const float* bv    = (const float*)d_in[6];
  const float* gamma = (const float*)d_in[7];
  float* out = (float*)d_out;

  const size_t WT_E = 320 * 256;
  const size_t QK_E = (size_t)4096 * 32;
  const size_t VT_E = (size_t)256 * 4096;
  size_t full_bytes = (WT_E + 4 * 2 * QK_E + 4 * VT_E) * sizeof(bf16);

  bf16* Wf = (bf16*)d_ws;
  prep_wt<<<dim3(256), dim3(320), 0, stream>>>(Wq, Wk, Wv, Wf);

  if (ws_size >= full_bytes) {
    bf16* Qd = Wf + WT_E;
    bf16* Kd = Qd + 4 * QK_E;
    bf16* Vt = Kd + 4 * QK_E;
    qkv_gemm<<<dim3(256), dim3(256), 0, stream>>>(x, Wf, bq, bk, bv, Qd, Kd, Vt);
    flash_attn<<<dim3(64, 4), dim3(512), 0, stream>>>(Qd, Kd, Vt, x, gamma, out);
  } else {
    bf16* Qd = Wf + WT_E;
    bf16* Kd = Qd + QK_E;
    bf16* Vt = Kd + QK_E;
    for (int b = 0; b < 4; ++b) {
      const float* xb = x + (size_t)b * 4096 * 256;
      float* outb = out + (size_t)b * 4096 * 256;
      qkv_gemm<<<dim3(64), dim3(256), 0, stream>>>(xb, Wf, bq, bk, bv, Qd, Kd, Vt);
      flash_attn<<<dim3(64, 1), dim3(512), 0, stream>>>(Qd, Kd, Vt, xb, gamma, outb);
    }
  }
}